// Round 2
// baseline (9512.849 us; speedup 1.0000x reference)
//
#include <hip/hip_runtime.h>
#include <math.h>
#include <stdint.h>

#define TT 64
#define OUTW 16896  // 512 + 4*4096

// ---------------- static device storage (re-filled every launch) ----------------
__device__ float WpreT[4098][512];   // W_pre^T  [k][j]
__device__ float WihT [512][1536];   // W_ih^T
__device__ float WhhT [512][1536];   // W_hh^T
__device__ float Wp1T [512][512];
__device__ float Wq1T [768][512];
__device__ float Wp2T [512][4096];
__device__ float Wq2T [512][4096];

__device__ float    g_h[2][32][512];   // deter state double buffer
__device__ float    g_x[32][512];      // pre-GRU activation
__device__ float    g_gx[32][1536];    // x @ W_ih^T (no bias)
__device__ float    g_gh[32][1536];    // h @ W_hh^T (no bias)
__device__ float    g_p1q1[32][1024];  // [0:512]=p1, [512:1024]=q1
__device__ unsigned g_qidx[32][64];    // posterior sample indices
__device__ unsigned g_cnt;             // grid barrier counter

struct Params {
  const float *obs, *act, *b_pre, *b_ih, *b_hh, *b_p1, *b_p2, *b_q1, *b_q2;
  float* out;
};

// ---------------- helpers ----------------
__device__ __forceinline__ float rdlane(float v, int l) {
  return __int_as_float(__builtin_amdgcn_readlane(__float_as_int(v), l));
}
__device__ __forceinline__ float sigm(float x) { return 1.0f / (1.0f + expf(-x)); }
__device__ __forceinline__ float siluf(float x) { return x * sigm(x); }

// torch-GRUCell step recompute (gates fused on the fly)
__device__ __forceinline__ float h2_of(const Params& P, const float* hprev, int b, int k) {
  float xr = g_gx[b][k],        hr = g_gh[b][k];
  float xu = g_gx[b][512 + k],  hu = g_gh[b][512 + k];
  float xn = g_gx[b][1024 + k], hn = g_gh[b][1024 + k];
  float r = sigm(xr + hr + P.b_ih[k] + P.b_hh[k]);
  float u = sigm(xu + hu + P.b_ih[512 + k] + P.b_hh[512 + k]);
  float n = tanhf(xn + P.b_ih[1024 + k] + r * (hn + P.b_hh[1024 + k]));
  return (1.0f - u) * n + u * hprev[b * 512 + k];
}

// Threefry-2x32, 20 rounds, key = (0, 42)  (jax.random.key(42))
__device__ __forceinline__ uint2 threefry_0_42(unsigned x0, unsigned x1) {
  const unsigned ks0 = 0u, ks1 = 42u, ks2 = 0x1BD11BDAu ^ 0u ^ 42u;
  x0 += ks0; x1 += ks1;
#define TFR(r) { x0 += x1; x1 = (x1 << r) | (x1 >> (32 - r)); x1 ^= x0; }
  TFR(13) TFR(15) TFR(26) TFR(6)   x0 += ks1; x1 += ks2 + 1u;
  TFR(17) TFR(29) TFR(16) TFR(24)  x0 += ks2; x1 += ks0 + 2u;
  TFR(13) TFR(15) TFR(26) TFR(6)   x0 += ks0; x1 += ks1 + 3u;
  TFR(17) TFR(29) TFR(16) TFR(24)  x0 += ks1; x1 += ks2 + 4u;
  TFR(13) TFR(15) TFR(26) TFR(6)   x0 += ks2; x1 += ks0 + 5u;
#undef TFR
  return make_uint2(x0, x1);
}

// JAX partitionable threefry random bits (jax_threefry_partitionable=True,
// default in modern JAX): element at 64-bit flat index i gets
// xor-fold of threefry2x32(key, (hi32(i), lo32(i))). Here size = 2^24 so hi=0.
__device__ __forceinline__ unsigned jax_bits_partitionable(unsigned flat) {
  uint2 o = threefry_0_42(0u, flat);
  return o.x ^ o.y;
}

// grid barrier: monotonic counter, agent-scope, full fences for cross-XCD visibility
__device__ __forceinline__ void gbar(unsigned target) {
  __syncthreads();
  if (threadIdx.x == 0) {
    __threadfence();
    __hip_atomic_fetch_add(&g_cnt, 1u, __ATOMIC_RELEASE, __HIP_MEMORY_SCOPE_AGENT);
    while (__hip_atomic_load(&g_cnt, __ATOMIC_RELAXED, __HIP_MEMORY_SCOPE_AGENT) < target)
      __builtin_amdgcn_s_sleep(2);
    __threadfence();
  }
  __syncthreads();
}

// gate matmul: dst[b][g*512+c] = sum_k vec[b][k] * W[k][g*512+c], 3 gates at once.
// 128 blocks: rel = (jb<<4)|bq ; wave kq covers k-range of 128; NB=2 batch rows.
__device__ __forceinline__ void gate_mm(const float (*W)[1536], const float* vec,
                                        float (*dst)[1536], int rel, int tid, float* lds) {
  const int lane = tid & 63, kq = tid >> 6;
  const int jb = rel >> 4, bq = rel & 15, b0 = bq * 2;
  const int c = jb * 64 + lane;
  const int k0 = kq * 128;
  float a00 = 0, a01 = 0, a10 = 0, a11 = 0, a20 = 0, a21 = 0;
  for (int kt = 0; kt < 128; kt += 64) {
    float v0 = vec[(b0 + 0) * 512 + k0 + kt + lane];
    float v1 = vec[(b0 + 1) * 512 + k0 + kt + lane];
#pragma unroll
    for (int kk = 0; kk < 64; ++kk) {
      const float* wr = &W[k0 + kt + kk][c];
      float w0 = wr[0], w1 = wr[512], w2 = wr[1024];
      float s0 = rdlane(v0, kk), s1 = rdlane(v1, kk);
      a00 = fmaf(s0, w0, a00); a01 = fmaf(s1, w0, a01);
      a10 = fmaf(s0, w1, a10); a11 = fmaf(s1, w1, a11);
      a20 = fmaf(s0, w2, a20); a21 = fmaf(s1, w2, a21);
    }
  }
  int base = (kq * 64 + lane) * 6;
  lds[base + 0] = a00; lds[base + 1] = a01; lds[base + 2] = a10;
  lds[base + 3] = a11; lds[base + 4] = a20; lds[base + 5] = a21;
  __syncthreads();
  for (int idx = tid; idx < 384; idx += 256) {
    int ln = idx % 64, w6 = idx / 64;
    float s = lds[(0 * 64 + ln) * 6 + w6] + lds[(1 * 64 + ln) * 6 + w6] +
              lds[(2 * 64 + ln) * 6 + w6] + lds[(3 * 64 + ln) * 6 + w6];
    int g = w6 >> 1, i = w6 & 1;
    dst[b0 + i][g * 512 + jb * 64 + ln] = s;
  }
}

// ---------------- setup kernels ----------------
__global__ void kzero() {
  unsigned i = blockIdx.x * 256 + threadIdx.x;
  if (i < 2u * 32u * 512u) ((float*)g_h)[i] = 0.0f;
  if (i == 0) g_cnt = 0u;
}

__device__ float* tr_dst(int sel) {
  switch (sel) {
    case 0: return &WpreT[0][0];
    case 1: return &WihT[0][0];
    case 2: return &WhhT[0][0];
    case 3: return &Wp1T[0][0];
    case 4: return &Wq1T[0][0];
    case 5: return &Wp2T[0][0];
    default: return &Wq2T[0][0];
  }
}

__global__ void ktranspose(const float* __restrict__ src, int sel, int R, int C) {
  __shared__ float tile[32][33];
  float* dst = tr_dst(sel);
  int c0 = blockIdx.x * 32, r0 = blockIdx.y * 32;
  int tx = threadIdx.x & 31, ty = threadIdx.x >> 5;
  for (int i = ty; i < 32; i += 8) {
    int r = r0 + i, c = c0 + tx;
    if (r < R && c < C) tile[i][tx] = src[(size_t)r * C + c];
  }
  __syncthreads();
  for (int i = ty; i < 32; i += 8) {
    int c = c0 + i, r = r0 + tx;
    if (c < C && r < R) dst[(size_t)c * R + r] = tile[tx][i];
  }
}

// ---------------- main persistent kernel ----------------
__global__ void __launch_bounds__(256) rssm_main(Params P) {
  const int bid = blockIdx.x, tid = threadIdx.x;
  const int lane = tid & 63, kq = tid >> 6;
  __shared__ float lds[5120];
  unsigned ph = 0;

  for (int t = 0; t < TT; ++t) {
    const float* hprev = &g_h[t & 1][0][0];
    float* hnext = &g_h[(t + 1) & 1][0][0];

    // ============ STAGE A: x (one-hot gather) on blocks 0..31 ; gh on 32..159 ============
    if (bid < 32) {
      const int b = bid;
      unsigned* qlds = (unsigned*)lds;
      if (t > 0 && tid < 64) qlds[tid] = g_qidx[b][tid];
      __syncthreads();
      float a0 = P.act[((size_t)b * TT + t) * 2 + 0];
      float a1 = P.act[((size_t)b * TT + t) * 2 + 1];
      for (int jj = tid; jj < 512; jj += 256) {
        float acc = P.b_pre[jj] + a0 * WpreT[4096][jj] + a1 * WpreT[4097][jj];
        if (t > 0) {
#pragma unroll 8
          for (int d = 0; d < 64; ++d) acc += WpreT[(d << 6) + qlds[d]][jj];
        }
        g_x[b][jj] = siluf(acc);
      }
    } else if (bid < 160) {
      gate_mm(WhhT, hprev, g_gh, bid - 32, tid, lds);
    }
    gbar(256u * (++ph));

    // ============ STAGE B: gx on blocks 0..127 ============
    if (bid < 128) {
      gate_mm(WihT, &g_x[0][0], g_gx, bid, tid, lds);
    }
    gbar(256u * (++ph));

    // ============ STAGE C: p1 (0..127), q1 (128..255), h2 write (jb==0 of p1) ============
    if (bid < 128) {
      const int jb = bid >> 4, bq = bid & 15, b0 = bq * 2;
      const int c = jb * 64 + lane;
      const int k0 = kq * 128;
      float a0 = 0, a1 = 0;
      for (int kt = 0; kt < 128; kt += 64) {
        float v0 = h2_of(P, hprev, b0 + 0, k0 + kt + lane);
        float v1 = h2_of(P, hprev, b0 + 1, k0 + kt + lane);
#pragma unroll
        for (int kk = 0; kk < 64; ++kk) {
          float w = Wp1T[k0 + kt + kk][c];
          a0 = fmaf(rdlane(v0, kk), w, a0);
          a1 = fmaf(rdlane(v1, kk), w, a1);
        }
      }
      int base = (kq * 64 + lane) * 2;
      lds[base] = a0; lds[base + 1] = a1;
      __syncthreads();
      for (int idx = tid; idx < 128; idx += 256) {
        int ln = idx & 63, i = idx >> 6;
        float s = lds[(0 * 64 + ln) * 2 + i] + lds[(1 * 64 + ln) * 2 + i] +
                  lds[(2 * 64 + ln) * 2 + i] + lds[(3 * 64 + ln) * 2 + i];
        s += P.b_p1[jb * 64 + ln];
        g_p1q1[b0 + i][jb * 64 + ln] = siluf(s);
      }
      if (jb == 0) {  // blocks 0..15 additionally materialize h2 -> hnext + deter output
        for (int idx = tid; idx < 1024; idx += 256) {
          int i = idx >> 9, k = idx & 511;
          float h2 = h2_of(P, hprev, b0 + i, k);
          hnext[(b0 + i) * 512 + k] = h2;
          P.out[((size_t)(b0 + i) * TT + t) * OUTW + k] = h2;
        }
      }
    } else {
      const int rel = bid - 128;
      const int jb = rel >> 4, bq = rel & 15, b0 = bq * 2;
      const int c = jb * 64 + lane;
      const int k0 = kq * 192;
      float a0 = 0, a1 = 0;
      for (int kt = 0; kt < 192; kt += 64) {
        int ks = k0 + kt;
        float v0, v1;
        if (ks < 512) {
          v0 = h2_of(P, hprev, b0 + 0, ks + lane);
          v1 = h2_of(P, hprev, b0 + 1, ks + lane);
        } else {
          v0 = P.obs[((size_t)(b0 + 0) * TT + t) * 256 + (ks - 512) + lane];
          v1 = P.obs[((size_t)(b0 + 1) * TT + t) * 256 + (ks - 512) + lane];
        }
#pragma unroll
        for (int kk = 0; kk < 64; ++kk) {
          float w = Wq1T[ks + kk][c];
          a0 = fmaf(rdlane(v0, kk), w, a0);
          a1 = fmaf(rdlane(v1, kk), w, a1);
        }
      }
      int base = (kq * 64 + lane) * 2;
      lds[base] = a0; lds[base + 1] = a1;
      __syncthreads();
      for (int idx = tid; idx < 128; idx += 256) {
        int ln = idx & 63, i = idx >> 6;
        float s = lds[(0 * 64 + ln) * 2 + i] + lds[(1 * 64 + ln) * 2 + i] +
                  lds[(2 * 64 + ln) * 2 + i] + lds[(3 * 64 + ln) * 2 + i];
        s += P.b_q1[jb * 64 + ln];
        g_p1q1[b0 + i][512 + jb * 64 + ln] = siluf(s);
      }
    }
    gbar(256u * (++ph));

    // ============ STAGE D: logits + softmax + gumbel sample (all 256 blocks) ============
    {
      const int n = bid >> 7;              // 0 = prior, 1 = posterior
      const int cb = (bid >> 3) & 15;      // column block: 256 cols = 4 d-groups
      const int bq = bid & 7;              // batch quad
      const int b0 = bq * 4;
      const int colbase = cb * 256;
      const float* W2 = n ? &Wq2T[0][0] : &Wp2T[0][0];
      const float* bias2 = n ? P.b_q2 : P.b_p2;
      const int k0 = kq * 128;
      float acc[4][4] = {{0}};
      for (int kt = 0; kt < 128; kt += 64) {
        float v[4];
#pragma unroll
        for (int i = 0; i < 4; ++i) v[i] = g_p1q1[b0 + i][n * 512 + k0 + kt + lane];
#pragma unroll
        for (int kk = 0; kk < 64; ++kk) {
          const float4 w = *(const float4*)&W2[(size_t)(k0 + kt + kk) * 4096 + colbase + lane * 4];
#pragma unroll
          for (int i = 0; i < 4; ++i) {
            float s = rdlane(v[i], kk);
            acc[i][0] = fmaf(s, w.x, acc[i][0]);
            acc[i][1] = fmaf(s, w.y, acc[i][1]);
            acc[i][2] = fmaf(s, w.z, acc[i][2]);
            acc[i][3] = fmaf(s, w.w, acc[i][3]);
          }
        }
      }
      float* red = lds;          // 4096 floats
      float* lg  = lds + 4096;   // 1024 floats: logits [i][256]
      int rb = (kq * 64 + lane) * 16;
#pragma unroll
      for (int i = 0; i < 4; ++i)
#pragma unroll
        for (int j = 0; j < 4; ++j) red[rb + i * 4 + j] = acc[i][j];
      __syncthreads();
      for (int idx = tid; idx < 1024; idx += 256) {
        int i = idx >> 8, cc = idx & 255;
        int ln = cc >> 2, j = cc & 3;
        float s = red[(0 * 64 + ln) * 16 + i * 4 + j] + red[(1 * 64 + ln) * 16 + i * 4 + j] +
                  red[(2 * 64 + ln) * 16 + i * 4 + j] + red[(3 * 64 + ln) * 16 + i * 4 + j];
        s += bias2[colbase + cc];
        lg[i * 256 + cc] = s;
        P.out[((size_t)(b0 + i) * TT + t) * OUTW + (n ? 12800 : 8704) + colbase + cc] = s;
      }
      __syncthreads();
      // sampling: wave kq owns b = b0+kq; 4 rounds over d-groups
      const int b = b0 + kq;
      for (int r = 0; r < 4; ++r) {
        const int d = cb * 4 + r;
        float L = lg[kq * 256 + r * 64 + lane];
        float m = L;
        for (int off = 1; off < 64; off <<= 1) m = fmaxf(m, __shfl_xor(m, off));
        float e = expf(L - m);
        float ssum = e;
        for (int off = 1; off < 64; off <<= 1) ssum += __shfl_xor(ssum, off);
        float p = 0.99f * (e / ssum) + (float)(0.01 / 64.0);
        // gumbel: JAX partitionable threefry bits (bits1 ^ bits2, counts = (0, flat64))
        unsigned flat = ((((unsigned)t * 32u + (unsigned)b) * 64u + (unsigned)d) * 64u +
                         (unsigned)lane) + ((unsigned)n << 23);
        unsigned bits = jax_bits_partitionable(flat);
        float f = __uint_as_float((bits >> 9) | 0x3f800000u) - 1.0f;
        float u = fmaxf(1e-9f, f + 1e-9f);
        float g = -logf(-logf(u));
        float y = logf(p) + g;
        float vm = y; int idxm = lane;
        for (int off = 1; off < 64; off <<= 1) {
          float v2 = __shfl_xor(vm, off);
          int i2 = __shfl_xor(idxm, off);
          if (v2 > vm || (v2 == vm && i2 < idxm)) { vm = v2; idxm = i2; }
        }
        P.out[((size_t)b * TT + t) * OUTW + (n ? 4608 : 512) + d * 64 + lane] =
            (lane == idxm) ? 1.0f : 0.0f;
        if (n == 1 && lane == 0) g_qidx[b][d] = (unsigned)idxm;
      }
    }
    gbar(256u * (++ph));
  }
}

// ---------------- host ----------------
extern "C" void kernel_launch(void* const* d_in, const int* in_sizes, int n_in,
                              void* d_out, int out_size, void* d_ws, size_t ws_size,
                              hipStream_t stream) {
  const float* obs   = (const float*)d_in[0];
  const float* act   = (const float*)d_in[1];
  const float* W_pre = (const float*)d_in[2];
  const float* b_pre = (const float*)d_in[3];
  const float* W_ih  = (const float*)d_in[4];
  const float* b_ih  = (const float*)d_in[5];
  const float* W_hh  = (const float*)d_in[6];
  const float* b_hh  = (const float*)d_in[7];
  const float* W_p1  = (const float*)d_in[8];
  const float* b_p1  = (const float*)d_in[9];
  const float* W_p2  = (const float*)d_in[10];
  const float* b_p2  = (const float*)d_in[11];
  const float* W_q1  = (const float*)d_in[12];
  const float* b_q1  = (const float*)d_in[13];
  const float* W_q2  = (const float*)d_in[14];
  const float* b_q2  = (const float*)d_in[15];

  kzero<<<128, 256, 0, stream>>>();
  auto tg = [](int R, int C) { return dim3((unsigned)((C + 31) / 32), (unsigned)((R + 31) / 32)); };
  ktranspose<<<tg(512, 4098), 256, 0, stream>>>(W_pre, 0, 512, 4098);
  ktranspose<<<tg(1536, 512), 256, 0, stream>>>(W_ih, 1, 1536, 512);
  ktranspose<<<tg(1536, 512), 256, 0, stream>>>(W_hh, 2, 1536, 512);
  ktranspose<<<tg(512, 512), 256, 0, stream>>>(W_p1, 3, 512, 512);
  ktranspose<<<tg(512, 768), 256, 0, stream>>>(W_q1, 4, 512, 768);
  ktranspose<<<tg(4096, 512), 256, 0, stream>>>(W_p2, 5, 4096, 512);
  ktranspose<<<tg(4096, 512), 256, 0, stream>>>(W_q2, 6, 4096, 512);

  Params P{obs, act, b_pre, b_ih, b_hh, b_p1, b_p2, b_q1, b_q2, (float*)d_out};
  rssm_main<<<dim3(256), dim3(256), 0, stream>>>(P);
}

// Round 3
// 5003.722 us; speedup vs baseline: 1.9012x; 1.9012x over previous
//
#include <hip/hip_runtime.h>
#include <math.h>
#include <stdint.h>

#define TT 64
#define OUTW 16896  // 512 + 4*4096

// ---------------- static device storage (re-filled every launch) ----------------
__device__ float WpreT[4098][512];   // W_pre^T  [k][j]
__device__ float WihT [512][1536];   // W_ih^T
__device__ float WhhT [512][1536];   // W_hh^T
__device__ float Wp1T [512][512];
__device__ float Wq1T [768][512];
__device__ float Wp2T [512][4096];
__device__ float Wq2T [512][4096];

// coherent-access-only arrays (NEVER touched by normal loads/stores in rssm_main)
__device__ float    g_h[2][32][512];   // deter state double buffer
__device__ float    g_x[32][512];      // pre-GRU activation
__device__ float    g_gx[32][1536];    // x @ W_ih^T (no bias)
__device__ float    g_gh[32][1536];    // h @ W_hh^T (no bias)
__device__ float    g_p1q1[32][1024];  // [0:512]=p1, [512:1024]=q1
__device__ unsigned g_qidx[32][64];    // posterior sample indices
__device__ unsigned g_flags[256 * 16]; // barrier arrival flags, 64B apart
__device__ unsigned g_go;              // barrier broadcast word

struct Params {
  const float *obs, *act, *b_pre, *b_ih, *b_hh, *b_p1, *b_p2, *b_q1, *b_q2;
  float* out;
};

// ---------------- coherent access helpers (relaxed, agent scope => sc0 sc1, no fences) ----------------
__device__ __forceinline__ float cload(const float* p) {
  return __hip_atomic_load((float*)p, __ATOMIC_RELAXED, __HIP_MEMORY_SCOPE_AGENT);
}
__device__ __forceinline__ void cstore(float* p, float v) {
  __hip_atomic_store(p, v, __ATOMIC_RELAXED, __HIP_MEMORY_SCOPE_AGENT);
}
__device__ __forceinline__ unsigned cuload(const unsigned* p) {
  return __hip_atomic_load((unsigned*)p, __ATOMIC_RELAXED, __HIP_MEMORY_SCOPE_AGENT);
}
__device__ __forceinline__ void custore(unsigned* p, unsigned v) {
  __hip_atomic_store(p, v, __ATOMIC_RELAXED, __HIP_MEMORY_SCOPE_AGENT);
}

// ---------------- misc helpers ----------------
__device__ __forceinline__ float rdlane(float v, int l) {
  return __int_as_float(__builtin_amdgcn_readlane(__float_as_int(v), l));
}
__device__ __forceinline__ float sigm(float x) { return 1.0f / (1.0f + expf(-x)); }
__device__ __forceinline__ float siluf(float x) { return x * sigm(x); }

// torch-GRUCell recompute from coherent gate buffers
__device__ __forceinline__ float h2_of(const Params& P, const float* hprev, int b, int k) {
  float xr = cload(&g_gx[b][k]),        hr = cload(&g_gh[b][k]);
  float xu = cload(&g_gx[b][512 + k]),  hu = cload(&g_gh[b][512 + k]);
  float xn = cload(&g_gx[b][1024 + k]), hn = cload(&g_gh[b][1024 + k]);
  float r = sigm(xr + hr + P.b_ih[k] + P.b_hh[k]);
  float u = sigm(xu + hu + P.b_ih[512 + k] + P.b_hh[512 + k]);
  float n = tanhf(xn + P.b_ih[1024 + k] + r * (hn + P.b_hh[1024 + k]));
  return (1.0f - u) * n + u * cload(&hprev[b * 512 + k]);
}

// Threefry-2x32, 20 rounds, key = (0, 42)
__device__ __forceinline__ uint2 threefry_0_42(unsigned x0, unsigned x1) {
  const unsigned ks0 = 0u, ks1 = 42u, ks2 = 0x1BD11BDAu ^ 0u ^ 42u;
  x0 += ks0; x1 += ks1;
#define TFR(r) { x0 += x1; x1 = (x1 << r) | (x1 >> (32 - r)); x1 ^= x0; }
  TFR(13) TFR(15) TFR(26) TFR(6)   x0 += ks1; x1 += ks2 + 1u;
  TFR(17) TFR(29) TFR(16) TFR(24)  x0 += ks2; x1 += ks0 + 2u;
  TFR(13) TFR(15) TFR(26) TFR(6)   x0 += ks0; x1 += ks1 + 3u;
  TFR(17) TFR(29) TFR(16) TFR(24)  x0 += ks1; x1 += ks2 + 4u;
  TFR(13) TFR(15) TFR(26) TFR(6)   x0 += ks2; x1 += ks0 + 5u;
#undef TFR
  return make_uint2(x0, x1);
}
__device__ __forceinline__ unsigned jax_bits_partitionable(unsigned flat) {
  uint2 o = threefry_0_42(0u, flat);
  return o.x ^ o.y;
}

// ---------------- fence-free grid barrier ----------------
// arrival: per-block flag store; detect: block0's 256 threads poll flags; release: go word.
__device__ __forceinline__ void gbar(int bid, int tid, unsigned p) {
  asm volatile("s_waitcnt vmcnt(0)" ::: "memory");  // each wave drains its coherent stores
  __syncthreads();
  if (tid == 0) custore(&g_flags[bid * 16], p);
  if (bid == 0) {
    while (cuload(&g_flags[tid * 16]) < p) __builtin_amdgcn_s_sleep(1);
    __syncthreads();
    if (tid == 0) custore(&g_go, p);
  } else {
    if (tid == 0) {
      while (cuload(&g_go) < p) __builtin_amdgcn_s_sleep(1);
    }
  }
  __syncthreads();
  asm volatile("" ::: "memory");
}

// gate matmul: dst[b][g*512+c] += vec-row ⋅ W-col, 3 gates at once, 2 batch rows.
// rel = jb + 8*bq  (jb in 0..7 selects the 64-col slice => XCD = bid&7 stable)
__device__ __forceinline__ void gate_mm(const float (*W)[1536], const float* vec,
                                        float (*dst)[1536], int rel, int tid, float* lds) {
  const int lane = tid & 63, kq = tid >> 6;
  const int jb = rel & 7, bq = rel >> 3, b0 = bq * 2;
  const int c = jb * 64 + lane;
  const int k0 = kq * 128;
  float a00 = 0, a01 = 0, a10 = 0, a11 = 0, a20 = 0, a21 = 0;
  for (int kt = 0; kt < 128; kt += 64) {
    float v0 = cload(&vec[(b0 + 0) * 512 + k0 + kt + lane]);
    float v1 = cload(&vec[(b0 + 1) * 512 + k0 + kt + lane]);
#pragma unroll
    for (int kk = 0; kk < 64; ++kk) {
      const float* wr = &W[k0 + kt + kk][c];
      float w0 = wr[0], w1 = wr[512], w2 = wr[1024];
      float s0 = rdlane(v0, kk), s1 = rdlane(v1, kk);
      a00 = fmaf(s0, w0, a00); a01 = fmaf(s1, w0, a01);
      a10 = fmaf(s0, w1, a10); a11 = fmaf(s1, w1, a11);
      a20 = fmaf(s0, w2, a20); a21 = fmaf(s1, w2, a21);
    }
  }
  int base = (kq * 64 + lane) * 6;
  lds[base + 0] = a00; lds[base + 1] = a01; lds[base + 2] = a10;
  lds[base + 3] = a11; lds[base + 4] = a20; lds[base + 5] = a21;
  __syncthreads();
  for (int idx = tid; idx < 384; idx += 256) {
    int ln = idx % 64, w6 = idx / 64;
    float s = lds[(0 * 64 + ln) * 6 + w6] + lds[(1 * 64 + ln) * 6 + w6] +
              lds[(2 * 64 + ln) * 6 + w6] + lds[(3 * 64 + ln) * 6 + w6];
    int g = w6 >> 1, i = w6 & 1;
    cstore(&dst[b0 + i][g * 512 + jb * 64 + ln], s);
  }
}

// ---------------- setup kernels ----------------
__global__ void kzero() {
  unsigned i = blockIdx.x * 256 + threadIdx.x;  // 128 blocks => i < 32768
  ((float*)g_h)[i] = 0.0f;
  if (i < 4096u) g_flags[i] = 0u;
  if (i == 0) g_go = 0u;
}

__device__ float* tr_dst(int sel) {
  switch (sel) {
    case 0: return &WpreT[0][0];
    case 1: return &WihT[0][0];
    case 2: return &WhhT[0][0];
    case 3: return &Wp1T[0][0];
    case 4: return &Wq1T[0][0];
    case 5: return &Wp2T[0][0];
    default: return &Wq2T[0][0];
  }
}

__global__ void ktranspose(const float* __restrict__ src, int sel, int R, int C) {
  __shared__ float tile[32][33];
  float* dst = tr_dst(sel);
  int c0 = blockIdx.x * 32, r0 = blockIdx.y * 32;
  int tx = threadIdx.x & 31, ty = threadIdx.x >> 5;
  for (int i = ty; i < 32; i += 8) {
    int r = r0 + i, c = c0 + tx;
    if (r < R && c < C) tile[i][tx] = src[(size_t)r * C + c];
  }
  __syncthreads();
  for (int i = ty; i < 32; i += 8) {
    int c = c0 + i, r = r0 + tx;
    if (c < C && r < R) dst[(size_t)c * R + r] = tile[tx][i];
  }
}

// ---------------- main persistent kernel ----------------
__global__ void __launch_bounds__(256) rssm_main(Params P) {
  const int bid = blockIdx.x, tid = threadIdx.x;
  const int lane = tid & 63, kq = tid >> 6;
  __shared__ float lds[5120];
  unsigned ph = 0;

  for (int t = 0; t < TT; ++t) {
    const float* hprev = &g_h[t & 1][0][0];
    float* hnext = &g_h[(t + 1) & 1][0][0];

    // ===== STAGE A: x (one-hot gather) on blocks 0..31 ; gh on 128..255 =====
    if (bid < 32) {
      const int b = bid;
      unsigned* qlds = (unsigned*)lds;
      if (t > 0 && tid < 64) qlds[tid] = cuload(&g_qidx[b][tid]);
      __syncthreads();
      float a0 = P.act[((size_t)b * TT + t) * 2 + 0];
      float a1 = P.act[((size_t)b * TT + t) * 2 + 1];
      for (int jj = tid; jj < 512; jj += 256) {
        float acc = P.b_pre[jj] + a0 * WpreT[4096][jj] + a1 * WpreT[4097][jj];
        if (t > 0) {
#pragma unroll 8
          for (int d = 0; d < 64; ++d)
            acc += __builtin_nontemporal_load(&WpreT[(d << 6) + qlds[d]][jj]);
        }
        cstore(&g_x[b][jj], siluf(acc));
      }
    } else if (bid >= 128) {
      gate_mm(WhhT, hprev, g_gh, bid - 128, tid, lds);
    }
    gbar(bid, tid, ++ph);

    // ===== STAGE B: gx on blocks 0..127 =====
    if (bid < 128) {
      gate_mm(WihT, &g_x[0][0], g_gx, bid, tid, lds);
    }
    gbar(bid, tid, ++ph);

    // ===== STAGE C: p1 (0..127), q1 (128..255); h2 materialized by jb==(bq&7) p1 blocks =====
    if (bid < 128) {
      const int jb = bid & 7, bq = bid >> 3, b0 = bq * 2;
      const int c = jb * 64 + lane;
      const int k0 = kq * 128;
      const bool mat = (jb == (bq & 7));
      float a0 = 0, a1 = 0;
      for (int kt = 0; kt < 128; kt += 64) {
        int k = k0 + kt + lane;
        float v0 = h2_of(P, hprev, b0 + 0, k);
        float v1 = h2_of(P, hprev, b0 + 1, k);
        if (mat) {
          cstore(&hnext[(b0 + 0) * 512 + k], v0);
          cstore(&hnext[(b0 + 1) * 512 + k], v1);
          __builtin_nontemporal_store(v0, &P.out[((size_t)(b0 + 0) * TT + t) * OUTW + k]);
          __builtin_nontemporal_store(v1, &P.out[((size_t)(b0 + 1) * TT + t) * OUTW + k]);
        }
#pragma unroll
        for (int kk = 0; kk < 64; ++kk) {
          float w = Wp1T[k0 + kt + kk][c];
          a0 = fmaf(rdlane(v0, kk), w, a0);
          a1 = fmaf(rdlane(v1, kk), w, a1);
        }
      }
      int base = (kq * 64 + lane) * 2;
      lds[base] = a0; lds[base + 1] = a1;
      __syncthreads();
      for (int idx = tid; idx < 128; idx += 256) {
        int ln = idx & 63, i = idx >> 6;
        float s = lds[(0 * 64 + ln) * 2 + i] + lds[(1 * 64 + ln) * 2 + i] +
                  lds[(2 * 64 + ln) * 2 + i] + lds[(3 * 64 + ln) * 2 + i];
        s += P.b_p1[jb * 64 + ln];
        cstore(&g_p1q1[b0 + i][jb * 64 + ln], siluf(s));
      }
    } else {
      const int rel = bid - 128;
      const int jb = rel & 7, bq = rel >> 3, b0 = bq * 2;
      const int c = jb * 64 + lane;
      const int k0 = kq * 192;
      float a0 = 0, a1 = 0;
      for (int kt = 0; kt < 192; kt += 64) {
        int ks = k0 + kt;
        float v0, v1;
        if (ks < 512) {
          v0 = h2_of(P, hprev, b0 + 0, ks + lane);
          v1 = h2_of(P, hprev, b0 + 1, ks + lane);
        } else {
          v0 = __builtin_nontemporal_load(&P.obs[((size_t)(b0 + 0) * TT + t) * 256 + (ks - 512) + lane]);
          v1 = __builtin_nontemporal_load(&P.obs[((size_t)(b0 + 1) * TT + t) * 256 + (ks - 512) + lane]);
        }
#pragma unroll
        for (int kk = 0; kk < 64; ++kk) {
          float w = Wq1T[ks + kk][c];
          a0 = fmaf(rdlane(v0, kk), w, a0);
          a1 = fmaf(rdlane(v1, kk), w, a1);
        }
      }
      int base = (kq * 64 + lane) * 2;
      lds[base] = a0; lds[base + 1] = a1;
      __syncthreads();
      for (int idx = tid; idx < 128; idx += 256) {
        int ln = idx & 63, i = idx >> 6;
        float s = lds[(0 * 64 + ln) * 2 + i] + lds[(1 * 64 + ln) * 2 + i] +
                  lds[(2 * 64 + ln) * 2 + i] + lds[(3 * 64 + ln) * 2 + i];
        s += P.b_q1[jb * 64 + ln];
        cstore(&g_p1q1[b0 + i][512 + jb * 64 + ln], siluf(s));
      }
    }
    gbar(bid, tid, ++ph);

    // ===== STAGE D: logits + softmax + gumbel sample (all 256 blocks) =====
    // bid = (n*16+cb) + 32*bq  => XCD = (n*16+cb)&7 stable per weight slice
    {
      const int bq = bid >> 5, nc = bid & 31;
      const int n = nc >> 4, cb = nc & 15;
      const int b0 = bq * 4;
      const int colbase = cb * 256;
      const float* W2 = n ? &Wq2T[0][0] : &Wp2T[0][0];
      const float* bias2 = n ? P.b_q2 : P.b_p2;
      const int k0 = kq * 128;
      float acc[4][4] = {{0}};
      for (int kt = 0; kt < 128; kt += 64) {
        float v[4];
#pragma unroll
        for (int i = 0; i < 4; ++i) v[i] = cload(&g_p1q1[b0 + i][n * 512 + k0 + kt + lane]);
#pragma unroll
        for (int kk = 0; kk < 64; ++kk) {
          const float4 w = *(const float4*)&W2[(size_t)(k0 + kt + kk) * 4096 + colbase + lane * 4];
#pragma unroll
          for (int i = 0; i < 4; ++i) {
            float s = rdlane(v[i], kk);
            acc[i][0] = fmaf(s, w.x, acc[i][0]);
            acc[i][1] = fmaf(s, w.y, acc[i][1]);
            acc[i][2] = fmaf(s, w.z, acc[i][2]);
            acc[i][3] = fmaf(s, w.w, acc[i][3]);
          }
        }
      }
      float* red = lds;          // 4096 floats
      float* lg  = lds + 4096;   // 1024 floats
      int rb = (kq * 64 + lane) * 16;
#pragma unroll
      for (int i = 0; i < 4; ++i)
#pragma unroll
        for (int j = 0; j < 4; ++j) red[rb + i * 4 + j] = acc[i][j];
      __syncthreads();
      for (int idx = tid; idx < 1024; idx += 256) {
        int i = idx >> 8, cc = idx & 255;
        int ln = cc >> 2, j = cc & 3;
        float s = red[(0 * 64 + ln) * 16 + i * 4 + j] + red[(1 * 64 + ln) * 16 + i * 4 + j] +
                  red[(2 * 64 + ln) * 16 + i * 4 + j] + red[(3 * 64 + ln) * 16 + i * 4 + j];
        s += bias2[colbase + cc];
        lg[i * 256 + cc] = s;
        __builtin_nontemporal_store(
            s, &P.out[((size_t)(b0 + i) * TT + t) * OUTW + (n ? 12800 : 8704) + colbase + cc]);
      }
      __syncthreads();
      const int b = b0 + kq;
      for (int r = 0; r < 4; ++r) {
        const int d = cb * 4 + r;
        float L = lg[kq * 256 + r * 64 + lane];
        float m = L;
        for (int off = 1; off < 64; off <<= 1) m = fmaxf(m, __shfl_xor(m, off));
        float e = expf(L - m);
        float ssum = e;
        for (int off = 1; off < 64; off <<= 1) ssum += __shfl_xor(ssum, off);
        float p = 0.99f * (e / ssum) + (float)(0.01 / 64.0);
        unsigned flat = ((((unsigned)t * 32u + (unsigned)b) * 64u + (unsigned)d) * 64u +
                         (unsigned)lane) + ((unsigned)n << 23);
        unsigned bits = jax_bits_partitionable(flat);
        float f = __uint_as_float((bits >> 9) | 0x3f800000u) - 1.0f;
        float u = fmaxf(1e-9f, f + 1e-9f);
        float g = -logf(-logf(u));
        float y = logf(p) + g;
        float vm = y; int idxm = lane;
        for (int off = 1; off < 64; off <<= 1) {
          float v2 = __shfl_xor(vm, off);
          int i2 = __shfl_xor(idxm, off);
          if (v2 > vm || (v2 == vm && i2 < idxm)) { vm = v2; idxm = i2; }
        }
        __builtin_nontemporal_store(
            (lane == idxm) ? 1.0f : 0.0f,
            &P.out[((size_t)b * TT + t) * OUTW + (n ? 4608 : 512) + d * 64 + lane]);
        if (n == 1 && lane == 0) custore(&g_qidx[b][d], (unsigned)idxm);
      }
    }
    gbar(bid, tid, ++ph);
  }
}

// ---------------- host ----------------
extern "C" void kernel_launch(void* const* d_in, const int* in_sizes, int n_in,
                              void* d_out, int out_size, void* d_ws, size_t ws_size,
                              hipStream_t stream) {
  const float* obs   = (const float*)d_in[0];
  const float* act   = (const float*)d_in[1];
  const float* W_pre = (const float*)d_in[2];
  const float* b_pre = (const float*)d_in[3];
  const float* W_ih  = (const float*)d_in[4];
  const float* b_ih  = (const float*)d_in[5];
  const float* W_hh  = (const float*)d_in[6];
  const float* b_hh  = (const float*)d_in[7];
  const float* W_p1  = (const float*)d_in[8];
  const float* b_p1  = (const float*)d_in[9];
  const float* W_p2  = (const float*)d_in[10];
  const float* b_p2  = (const float*)d_in[11];
  const float* W_q1  = (const float*)d_in[12];
  const float* b_q1  = (const float*)d_in[13];
  const float* W_q2  = (const float*)d_in[14];
  const float* b_q2  = (const float*)d_in[15];

  kzero<<<128, 256, 0, stream>>>();
  auto tg = [](int R, int C) { return dim3((unsigned)((C + 31) / 32), (unsigned)((R + 31) / 32)); };
  ktranspose<<<tg(512, 4098), 256, 0, stream>>>(W_pre, 0, 512, 4098);
  ktranspose<<<tg(1536, 512), 256, 0, stream>>>(W_ih, 1, 1536, 512);
  ktranspose<<<tg(1536, 512), 256, 0, stream>>>(W_hh, 2, 1536, 512);
  ktranspose<<<tg(512, 512), 256, 0, stream>>>(W_p1, 3, 512, 512);
  ktranspose<<<tg(512, 768), 256, 0, stream>>>(W_q1, 4, 512, 768);
  ktranspose<<<tg(4096, 512), 256, 0, stream>>>(W_p2, 5, 4096, 512);
  ktranspose<<<tg(4096, 512), 256, 0, stream>>>(W_q2, 6, 4096, 512);

  Params P{obs, act, b_pre, b_ih, b_hh, b_p1, b_p2, b_q1, b_q2, (float*)d_out};
  rssm_main<<<dim3(256), dim3(256), 0, stream>>>(P);
}